// Round 9
// baseline (218.455 us; speedup 1.0000x reference)
//
#include <hip/hip_runtime.h>

typedef unsigned short u16;
typedef unsigned int u32;
typedef __bf16 bf16x8 __attribute__((ext_vector_type(8)));
typedef float f32x4 __attribute__((ext_vector_type(4)));
typedef u16 u16x8 __attribute__((ext_vector_type(8)));

__device__ __forceinline__ u16 f2bf(float f) {
    __bf16 h = (__bf16)f;
    return __builtin_bit_cast(u16, h);
}
__device__ __forceinline__ float bf2f(u16 u) {
    unsigned int x = ((unsigned int)u) << 16;
    return __builtin_bit_cast(float, x);
}

union FragU { u16x8 u; bf16x8 v; };

// ---------------- workspace layout (float offsets) ----------------
constexpr size_t WB2F  = 0;        // 18432 f = 36864 u16 : frw2 bf16 [tap][och][cin]
constexpr size_t WB3F  = 18432;    // 18432 : frw3
constexpr size_t WBV2  = 36864;    // 18432 : vrw2
constexpr size_t W1T   = 55296;    // 2048 f = 4096 u16 : mw1 rows 1..64, [col][row-1]
constexpr size_t W2T   = 57344;    // 2048 : mw2 transposed [j2][j1]
constexpr size_t X1    = 59392;    // 258048 f = 4*2016*64 u16 (ch-last bf16)
constexpr size_t X2    = 317440;   // 258048
constexpr size_t FEATBF= 575488;   // 258048
constexpr size_t NOVEL = 833536;   // 14336 : [b*7+v][1024] f32
constexpr size_t Y1    = 847872;   // 458752 f = 14*1024*64 u16
constexpr size_t Y2    = 1306624;  // 458752
// total ~1765376 f = 7.06 MB

// ================= prep: one-time weight convert/transpose =================
__global__ __launch_bounds__(256) void prep_kernel(
    const float* __restrict__ frw2, const float* __restrict__ frw3,
    const float* __restrict__ vrw2,
    const float* __restrict__ mw1, const float* __restrict__ mw2,
    u16* __restrict__ wb2, u16* __restrict__ wb3, u16* __restrict__ wbv,
    u16* __restrict__ w1t, u16* __restrict__ w2t)
{
    const int tid = blockIdx.x * 256 + threadIdx.x;
    const int stride = gridDim.x * 256;
    for (int i = tid; i < 36864; i += stride) {
        int tap = i >> 12, och = (i >> 6) & 63, cin = i & 63;
        size_t s = (size_t)och * 576 + cin * 9 + tap;
        wb2[i] = f2bf(frw2[s]);
        wb3[i] = f2bf(frw3[s]);
        wbv[i] = f2bf(vrw2[s]);
    }
    for (int i = tid; i < 4096; i += stride) {
        int col = i >> 6, r = i & 63;
        w1t[i] = f2bf(mw1[(1 + r) * 64 + col]);   // W1T[col][r] = w1[1+r][col]
        w2t[i] = f2bf(mw2[r * 64 + col]);         // W2T[j2=col][j1=r] = w2[r][col]
    }
}

// ================= conv1: 3ch -> 64, VALU, ch-last bf16 out ===============
template<int W, int NPX>
__global__ __launch_bounds__(256) void conv1_kernel(
    const float* __restrict__ in0, const float* __restrict__ in1,
    const float* __restrict__ in2,
    const float* __restrict__ wts, const float* __restrict__ bias,
    u16* __restrict__ out)
{
    constexpr int H = 32;
    const int t = threadIdx.x;
    const int px = blockIdx.y * 256 + t;
    const int m = blockIdx.z;
    const int og = blockIdx.x;
    if (px >= NPX) return;
    const int y = px / W, x = px - y * W;

    float acc[8];
#pragma unroll
    for (int oc = 0; oc < 8; ++oc) acc[oc] = bias[og * 8 + oc];

#pragma unroll
    for (int cin = 0; cin < 3; ++cin) {
        const float* ip = (cin == 0 ? in0 : (cin == 1 ? in1 : in2)) + (size_t)m * NPX;
        float tap[9];
#pragma unroll
        for (int dy = 0; dy < 3; ++dy) {
            int yy = y + dy - 1;
            bool ry = (yy >= 0) && (yy < H);
#pragma unroll
            for (int dx = 0; dx < 3; ++dx) {
                int xx = x + dx - 1;
                tap[dy * 3 + dx] = (ry && xx >= 0 && xx < W) ? ip[yy * W + xx] : 0.f;
            }
        }
#pragma unroll
        for (int oc = 0; oc < 8; ++oc) {
            const float* wr = wts + (size_t)(og * 8 + oc) * 27 + cin * 9;
#pragma unroll
            for (int j = 0; j < 9; ++j) acc[oc] = fmaf(tap[j], wr[j], acc[oc]);
        }
    }
    u16x8 pk;
#pragma unroll
    for (int oc = 0; oc < 8; ++oc) pk[oc] = f2bf(fmaxf(acc[oc], 0.f));
    *(u16x8*)(out + ((size_t)m * NPX + px) * 64 + og * 8) = pk;
}

// ================= convMFMA v2: weights direct from global bf16 ===========
// in/out ch-last bf16 [M][NPX][64]. wbf = bf16 [tap][och][cin] (prep).
// Block = 64 px x 64 och; B-frags are aligned 16B global loads (L2-hot,
// 72KB tensor); A-frags predicated 16B loads. No LDS at all.
// Fragment maps identical to the r8-verified kernel.
template<int W, int NPX>
__global__ __launch_bounds__(256) void convmfma_kernel(
    const u16* __restrict__ in, const u16* __restrict__ wbf,
    const float* __restrict__ bias, u16* __restrict__ out)
{
    constexpr int H = 32;
    const int t = threadIdx.x;
    const int base = blockIdx.x * 64;
    const int m = blockIdx.y;
    const int w = t >> 6, lane = t & 63, q = lane >> 4, l15 = lane & 15;

    const u16* im = in + (size_t)m * NPX * 64;
    const int pxA = base + w * 16 + l15;
    const int yA = pxA / W, xA = pxA - yA * W;
    const bool pxok = (pxA < NPX);

    f32x4 acc[4];
#pragma unroll
    for (int nt = 0; nt < 4; ++nt) acc[nt] = f32x4{0.f, 0.f, 0.f, 0.f};

#pragma unroll
    for (int tap = 0; tap < 9; ++tap) {
        const int dy = tap / 3 - 1, dx = tap % 3 - 1;
        const bool valid = pxok && (yA + dy >= 0) && (yA + dy < H)
                                && (xA + dx >= 0) && (xA + dx < W);
        const u16* ap = im + (size_t)(pxA + dy * W + dx) * 64;
        FragU a0, a1;
        if (valid) {
            a0 = *(const FragU*)(ap + q * 8);
            a1 = *(const FragU*)(ap + 32 + q * 8);
        } else {
#pragma unroll
            for (int jj = 0; jj < 8; ++jj) { a0.u[jj] = 0; a1.u[jj] = 0; }
        }
#pragma unroll
        for (int nt = 0; nt < 4; ++nt) {
            const u16* bp = wbf + tap * 4096 + (nt * 16 + l15) * 64;
            FragU b0 = *(const FragU*)(bp + q * 8);
            FragU b1 = *(const FragU*)(bp + 32 + q * 8);
            acc[nt] = __builtin_amdgcn_mfma_f32_16x16x32_bf16(a0.v, b0.v, acc[nt], 0, 0, 0);
            acc[nt] = __builtin_amdgcn_mfma_f32_16x16x32_bf16(a1.v, b1.v, acc[nt], 0, 0, 0);
        }
    }

#pragma unroll
    for (int nt = 0; nt < 4; ++nt) {
        const float bb = bias[nt * 16 + l15];
#pragma unroll
        for (int e = 0; e < 4; ++e) {
            int pxs = base + w * 16 + q * 4 + e;
            if (pxs < NPX)
                out[((size_t)m * NPX + pxs) * 64 + nt * 16 + l15] =
                    f2bf(fmaxf(acc[nt][e] + bb, 0.f));
        }
    }
}

// ================= MLP + softmax + epi + conf-combine (r6-verified struct) =
// 256 blocks (2 b x 128 n-groups of 8), 2 iters of 4 n; both s in-block
// (waves 0-1: s=0, waves 2-3: s=1). Weight frags direct from W1T/W2T global.
__global__ __launch_bounds__(256, 2) void mlp_mfma_kernel(
    const float* __restrict__ lf, const float* __restrict__ flow,
    const u16* __restrict__ feat,   // [bs][2016][64] bf16
    const u16* __restrict__ w1t, const u16* __restrict__ w2t,
    const float* __restrict__ w1, const float* __restrict__ b1,
    const float* __restrict__ b2,
    const float* __restrict__ w3, const float* __restrict__ b3g,
    const float* __restrict__ cw, const float* __restrict__ cbg,
    float* __restrict__ novel)      // [b*7+v][1024] f32
{
    constexpr int SBS = 72;
    __shared__ __align__(16) float s_vec[7 * 64];
    __shared__ __align__(16) float s_flow[256];
    __shared__ __align__(16) float s_epi[256];
    __shared__ __align__(16) u16 s_base[256 * SBS];
    __shared__ float s_nv[2][7][4];
    __shared__ float s_cf[2][7][4];

    const int t = threadIdx.x;
    const int blk = blockIdx.x;
    const int b = blk >> 7;
    const int n0base = (blk & 127) * 8;
    const int w = t >> 6, lane = t & 63, q = lane >> 4, l15 = lane & 15;
    const int sw = w >> 1;
    const int bsw = b * 2 + sw;

    if (t < 64) {
        s_vec[t]       = b1[t];
        s_vec[64 + t]  = b2[t];
        s_vec[128 + t] = w3[t];
        s_vec[192 + t] = cw[t];
        s_vec[256 + t] = w1[t];            // row 0: flow weight
        s_vec[320 + t] = w1[65 * 64 + t];  // row 65: spatial
        s_vec[384 + t] = w1[66 * 64 + t];  // row 66: ang
    }
    __syncthreads();

    const float b3s = b3g[0];
    const float cbs = cbg[0];

    // weight fragments: aligned 16B loads from pre-transposed global bf16
    FragU w1b[2][4];
#pragma unroll
    for (int ks = 0; ks < 2; ++ks)
#pragma unroll
        for (int nt = 0; nt < 4; ++nt)
            w1b[ks][nt] = *(const FragU*)(w1t + (nt * 16 + l15) * 64 + ks * 32 + q * 8);

    FragU w2a[4][2]; // A = W2^T
#pragma unroll
    for (int mt = 0; mt < 4; ++mt)
#pragma unroll
        for (int ks = 0; ks < 2; ++ks)
            w2a[mt][ks] = *(const FragU*)(w2t + (mt * 16 + l15) * 64 + ks * 32 + q * 8);

    float w1r0pl[4], w1r65pl[4], b1pl[4];
#pragma unroll
    for (int nt = 0; nt < 4; ++nt) {
        int j1 = nt * 16 + l15;
        w1r0pl[nt]  = s_vec[256 + j1];
        w1r65pl[nt] = s_vec[320 + j1];
        b1pl[nt]    = s_vec[j1];
    }
    float w66pl[2][8];
#pragma unroll
    for (int ks = 0; ks < 2; ++ks)
#pragma unroll
        for (int jj = 0; jj < 8; ++jj)
            w66pl[ks][jj] = s_vec[384 + ks * 32 + q * 8 + jj];
    float b2pl[4][4], w3pl[4][4], cwpl[4][4];
#pragma unroll
    for (int mt = 0; mt < 4; ++mt)
#pragma unroll
        for (int e = 0; e < 4; ++e) {
            b2pl[mt][e] = s_vec[64 + mt * 16 + q * 4 + e];
            w3pl[mt][e] = s_vec[128 + mt * 16 + q * 4 + e];
            cwpl[mt][e] = s_vec[192 + mt * 16 + q * 4 + e];
        }

#pragma unroll 1
    for (int iter = 0; iter < 2; ++iter) {
        const int n0 = n0base + iter * 4;
        {
            int ss = t >> 7, nl = (t >> 5) & 3, k = t & 31;
            int n = n0 + nl;
            int a = ((b * 2 + ss) * 32 + (n >> 5)) * 63 + (n & 31) + k;
            s_flow[t] = flow[a];
            s_epi[t]  = lf[a];
        }
        __syncthreads();

        // ---- layer 1 ----
#pragma unroll
        for (int mt = 0; mt < 4; ++mt) {
            const int rbase = w * 64 + mt * 16;
            FragU af[2];
            {
                int r = rbase + l15;
                int n = n0 + ((r >> 5) & 3);
                int pos = (n >> 5) * 63 + (n & 31) + (r & 31);
                const u16* fp = feat + ((size_t)bsw * 2016 + pos) * 64;
                af[0] = *(const FragU*)(fp + q * 8);
                af[1] = *(const FragU*)(fp + 32 + q * 8);
            }
            f32x4 flow4 = *(const f32x4*)(s_flow + rbase + q * 4);
#pragma unroll
            for (int nt = 0; nt < 4; ++nt) {
                f32x4 d = {0.f, 0.f, 0.f, 0.f};
                d = __builtin_amdgcn_mfma_f32_16x16x32_bf16(af[0].v, w1b[0][nt].v, d, 0, 0, 0);
                d = __builtin_amdgcn_mfma_f32_16x16x32_bf16(af[1].v, w1b[1][nt].v, d, 0, 0, 0);
#pragma unroll
                for (int e = 0; e < 4; ++e) {
                    int r = rbase + q * 4 + e;
                    int k = r & 31;
                    float val = d[e] + flow4[e] * w1r0pl[nt]
                              + (float)(k - 16) * w1r65pl[nt] + b1pl[nt];
                    s_base[r * SBS + nt * 16 + l15] = f2bf(val);
                }
            }
        }
        __syncthreads();

        float epi_pl[4];
#pragma unroll
        for (int nt = 0; nt < 4; ++nt) epi_pl[nt] = s_epi[w * 64 + nt * 16 + l15];

        // ---- per-view loop ----
        for (int v = 0; v < 7; ++v) {
            float ang = (sw == 0) ? -(float)(v + 1) : (float)(7 - v);
            f32x4 acc[4][4];
#pragma unroll
            for (int nt = 0; nt < 4; ++nt) {
                FragU bfr[2];
#pragma unroll
                for (int ks = 0; ks < 2; ++ks) {
                    const u16x8 raw = *(const u16x8*)(s_base + (w * 64 + nt * 16 + l15) * SBS + ks * 32 + q * 8);
#pragma unroll
                    for (int jj = 0; jj < 8; ++jj) {
                        float xv = bf2f(raw[jj]);
                        float hv = fmaxf(xv + ang * w66pl[ks][jj], 0.f);
                        bfr[ks].u[jj] = f2bf(hv);
                    }
                }
#pragma unroll
                for (int mt = 0; mt < 4; ++mt) {
                    f32x4 d = {0.f, 0.f, 0.f, 0.f};
                    d = __builtin_amdgcn_mfma_f32_16x16x32_bf16(w2a[mt][0].v, bfr[0].v, d, 0, 0, 0);
                    d = __builtin_amdgcn_mfma_f32_16x16x32_bf16(w2a[mt][1].v, bfr[1].v, d, 0, 0, 0);
                    acc[mt][nt] = d;
                }
            }
            float wl[4], cfl[4];
#pragma unroll
            for (int nt = 0; nt < 4; ++nt) {
                float wls = 0.f, cfs = 0.f;
#pragma unroll
                for (int mt = 0; mt < 4; ++mt)
#pragma unroll
                    for (int e = 0; e < 4; ++e) {
                        float h2 = fmaxf(acc[mt][nt][e] + b2pl[mt][e], 0.f);
                        wls += h2 * w3pl[mt][e];
                        cfs += h2 * cwpl[mt][e];
                    }
                wls += __shfl_xor(wls, 16); wls += __shfl_xor(wls, 32);
                cfs += __shfl_xor(cfs, 16); cfs += __shfl_xor(cfs, 32);
                wl[nt]  = wls + b3s;
                cfl[nt] = cfs;
            }
#pragma unroll
            for (int ni = 0; ni < 2; ++ni) {
                float a0 = wl[ni * 2], a1 = wl[ni * 2 + 1];
                float mx = fmaxf(a0, a1);
#pragma unroll
                for (int msk = 1; msk <= 8; msk <<= 1) mx = fmaxf(mx, __shfl_xor(mx, msk));
                float e0 = __expf(a0 - mx), e1 = __expf(a1 - mx);
                float ssum = e0 + e1;
                float nvp = e0 * epi_pl[ni * 2] + e1 * epi_pl[ni * 2 + 1];
                float cfp = cfl[ni * 2] + cfl[ni * 2 + 1];
#pragma unroll
                for (int msk = 1; msk <= 8; msk <<= 1) {
                    ssum += __shfl_xor(ssum, msk);
                    nvp  += __shfl_xor(nvp, msk);
                    cfp  += __shfl_xor(cfp, msk);
                }
                if (lane == 0) {
                    int nloc = (w & 1) * 2 + ni;
                    s_nv[sw][v][nloc] = nvp / ssum;
                    s_cf[sw][v][nloc] = cfp * (1.f / 32.f) + cbs;
                }
            }
        }
        __syncthreads();

        // ---- conf softmax over s + write novel ----
        if (t < 28) {
            int v = t >> 2, nl = t & 3;
            float c0 = s_cf[0][v][nl], c1 = s_cf[1][v][nl];
            float mx = fmaxf(c0, c1);
            float e0 = __expf(c0 - mx), e1 = __expf(c1 - mx);
            novel[(size_t)(b * 7 + v) * 1024 + n0 + nl] =
                (e0 * s_nv[0][v][nl] + e1 * s_nv[1][v][nl]) / (e0 + e1);
        }
    }
}

// ================= convlast: 64 -> 1 + bias + residual =====================
__global__ __launch_bounds__(256) void convlast_kernel(
    const u16* __restrict__ in,     // [14][1024][64] bf16 ch-last
    const float* __restrict__ wts,  // [64][9]
    const float* __restrict__ bias, // [1]
    const float* __restrict__ resid,// [14][1024] f32
    float* __restrict__ out)        // [14][1024] f32
{
    __shared__ float sw3[576];
    const int t = threadIdx.x;
    for (int i = t; i < 576; i += 256) sw3[i] = wts[i];
    __syncthreads();

    const int tid = blockIdx.x * 256 + t;
    const int m = tid >> 10, p = tid & 1023;
    const int y = p >> 5, x = p & 31;
    float a = bias[0] + resid[tid];
    const u16* im = in + ((size_t)m * 1024 + p) * 64;
#pragma unroll
    for (int dy = 0; dy < 3; ++dy) {
        int yy = y + dy - 1;
        if (yy < 0 || yy >= 32) continue;
#pragma unroll
        for (int dx = 0; dx < 3; ++dx) {
            int xx = x + dx - 1;
            if (xx < 0 || xx >= 32) continue;
            const u16* ip = im + (size_t)((dy - 1) * 32 + (dx - 1)) * 64;
            const int tap = dy * 3 + dx;
#pragma unroll
            for (int cg = 0; cg < 8; ++cg) {
                u16x8 raw = *(const u16x8*)(ip + cg * 8);
#pragma unroll
                for (int e = 0; e < 8; ++e)
                    a = fmaf(bf2f(raw[e]), sw3[(cg * 8 + e) * 9 + tap], a);
            }
        }
    }
    out[tid] = a;
}

// ---------------- launch ----------------
extern "C" void kernel_launch(void* const* d_in, const int* in_sizes, int n_in,
                              void* d_out, int out_size, void* d_ws, size_t ws_size,
                              hipStream_t stream) {
    const float* lf   = (const float*)d_in[0];
    const float* flow = (const float*)d_in[1];
    const float* wp   = (const float*)d_in[2];
    const float* pl   = (const float*)d_in[3];
    const float* pr   = (const float*)d_in[4];
    float* ws = (float*)d_ws;

    prep_kernel<<<128, 256, 0, stream>>>(
        (const float*)d_in[7], (const float*)d_in[9], (const float*)d_in[21],
        (const float*)d_in[11], (const float*)d_in[13],
        (u16*)(ws + WB2F), (u16*)(ws + WB3F), (u16*)(ws + WBV2),
        (u16*)(ws + W1T), (u16*)(ws + W2T));

    // feature net (4 images, 32x63, ch-last bf16 pipeline)
    conv1_kernel<63, 2016><<<dim3(8, 8, 4), 256, 0, stream>>>(
        flow, lf, wp, (const float*)d_in[5], (const float*)d_in[6],
        (u16*)(ws + X1));
    convmfma_kernel<63, 2016><<<dim3(32, 4), 256, 0, stream>>>(
        (const u16*)(ws + X1), (const u16*)(ws + WB2F), (const float*)d_in[8],
        (u16*)(ws + X2));
    convmfma_kernel<63, 2016><<<dim3(32, 4), 256, 0, stream>>>(
        (const u16*)(ws + X2), (const u16*)(ws + WB3F), (const float*)d_in[10],
        (u16*)(ws + FEATBF));

    // MLP + softmax + epi + conf-combine -> novel
    mlp_mfma_kernel<<<256, 256, 0, stream>>>(
        lf, flow, (const u16*)(ws + FEATBF),
        (const u16*)(ws + W1T), (const u16*)(ws + W2T),
        (const float*)d_in[11], (const float*)d_in[12],
        (const float*)d_in[14],
        (const float*)d_in[15], (const float*)d_in[16],
        (const float*)d_in[17], (const float*)d_in[18],
        ws + NOVEL);

    // refinement net (14 images, 32x32)
    conv1_kernel<32, 1024><<<dim3(8, 4, 14), 256, 0, stream>>>(
        ws + NOVEL, pl, pr, (const float*)d_in[19], (const float*)d_in[20],
        (u16*)(ws + Y1));
    convmfma_kernel<32, 1024><<<dim3(16, 14), 256, 0, stream>>>(
        (const u16*)(ws + Y1), (const u16*)(ws + WBV2), (const float*)d_in[22],
        (u16*)(ws + Y2));
    convlast_kernel<<<56, 256, 0, stream>>>(
        (const u16*)(ws + Y2), (const float*)d_in[23], (const float*)d_in[24],
        ws + NOVEL, (float*)d_out);
}

// Round 10
// 195.811 us; speedup vs baseline: 1.1156x; 1.1156x over previous
//
#include <hip/hip_runtime.h>

typedef unsigned short u16;
typedef unsigned int u32;
typedef __bf16 bf16x8 __attribute__((ext_vector_type(8)));
typedef float f32x4 __attribute__((ext_vector_type(4)));
typedef u16 u16x8 __attribute__((ext_vector_type(8)));

__device__ __forceinline__ u16 f2bf(float f) {
    __bf16 h = (__bf16)f;
    return __builtin_bit_cast(u16, h);
}
__device__ __forceinline__ float bf2f(u16 u) {
    unsigned int x = ((unsigned int)u) << 16;
    return __builtin_bit_cast(float, x);
}

union FragU { u16x8 u; bf16x8 v; };

// ---------------- workspace layout (float offsets) ----------------
constexpr size_t WB2F  = 0;        // 18432 f = 36864 u16 : frw2 bf16 [tap][och][cin]
constexpr size_t WB3F  = 18432;    // 18432 : frw3
constexpr size_t WBV2  = 36864;    // 18432 : vrw2
constexpr size_t W1T   = 55296;    // 2048 f = 4096 u16 : mw1 rows 1..64, [col][row-1]
constexpr size_t W2T   = 57344;    // 2048 : mw2 transposed [j2][j1]
constexpr size_t X1    = 59392;    // 258048 f = 4*2016*64 u16 (ch-last bf16)
constexpr size_t X2    = 317440;   // 258048
constexpr size_t FEATBF= 575488;   // 258048
constexpr size_t NVOFF = 833536;   // 28672 : [(b*7+v)*2+s][1024]
constexpr size_t CFOFF = 862208;   // 28672
constexpr size_t NOVEL = 890880;   // 14336 : [b*7+v][1024] f32
constexpr size_t Y1    = 905216;   // 458752 f = 14*1024*64 u16
constexpr size_t Y2    = 1363968;  // 458752
// total ~1822720 f = 7.3 MB

// ================= prep: one-time weight convert/transpose =================
__global__ __launch_bounds__(256) void prep_kernel(
    const float* __restrict__ frw2, const float* __restrict__ frw3,
    const float* __restrict__ vrw2,
    const float* __restrict__ mw1, const float* __restrict__ mw2,
    u16* __restrict__ wb2, u16* __restrict__ wb3, u16* __restrict__ wbv,
    u16* __restrict__ w1t, u16* __restrict__ w2t)
{
    const int tid = blockIdx.x * 256 + threadIdx.x;
    const int stride = gridDim.x * 256;
    for (int i = tid; i < 36864; i += stride) {
        int tap = i >> 12, och = (i >> 6) & 63, cin = i & 63;
        size_t s = (size_t)och * 576 + cin * 9 + tap;
        wb2[i] = f2bf(frw2[s]);
        wb3[i] = f2bf(frw3[s]);
        wbv[i] = f2bf(vrw2[s]);
    }
    for (int i = tid; i < 4096; i += stride) {
        int col = i >> 6, r = i & 63;
        w1t[i] = f2bf(mw1[(1 + r) * 64 + col]);   // W1T[col][r] = w1[1+r][col]
        w2t[i] = f2bf(mw2[r * 64 + col]);         // W2T[j2=col][j1=r] = w2[r][col]
    }
}

// ================= conv1: 3ch -> 64, VALU, ch-last bf16 out ===============
template<int W, int NPX>
__global__ __launch_bounds__(256) void conv1_kernel(
    const float* __restrict__ in0, const float* __restrict__ in1,
    const float* __restrict__ in2,
    const float* __restrict__ wts, const float* __restrict__ bias,
    u16* __restrict__ out)
{
    constexpr int H = 32;
    const int t = threadIdx.x;
    const int px = blockIdx.y * 256 + t;
    const int m = blockIdx.z;
    const int og = blockIdx.x;
    if (px >= NPX) return;
    const int y = px / W, x = px - y * W;

    float acc[8];
#pragma unroll
    for (int oc = 0; oc < 8; ++oc) acc[oc] = bias[og * 8 + oc];

#pragma unroll
    for (int cin = 0; cin < 3; ++cin) {
        const float* ip = (cin == 0 ? in0 : (cin == 1 ? in1 : in2)) + (size_t)m * NPX;
        float tap[9];
#pragma unroll
        for (int dy = 0; dy < 3; ++dy) {
            int yy = y + dy - 1;
            bool ry = (yy >= 0) && (yy < H);
#pragma unroll
            for (int dx = 0; dx < 3; ++dx) {
                int xx = x + dx - 1;
                tap[dy * 3 + dx] = (ry && xx >= 0 && xx < W) ? ip[yy * W + xx] : 0.f;
            }
        }
#pragma unroll
        for (int oc = 0; oc < 8; ++oc) {
            const float* wr = wts + (size_t)(og * 8 + oc) * 27 + cin * 9;
#pragma unroll
            for (int j = 0; j < 9; ++j) acc[oc] = fmaf(tap[j], wr[j], acc[oc]);
        }
    }
    u16x8 pk;
#pragma unroll
    for (int oc = 0; oc < 8; ++oc) pk[oc] = f2bf(fmaxf(acc[oc], 0.f));
    *(u16x8*)(out + ((size_t)m * NPX + px) * 64 + og * 8) = pk;
}

// ================= convMFMA: weights direct from global bf16 ===============
template<int W, int NPX>
__global__ __launch_bounds__(256) void convmfma_kernel(
    const u16* __restrict__ in, const u16* __restrict__ wbf,
    const float* __restrict__ bias, u16* __restrict__ out)
{
    constexpr int H = 32;
    const int t = threadIdx.x;
    const int base = blockIdx.x * 64;
    const int m = blockIdx.y;
    const int w = t >> 6, lane = t & 63, q = lane >> 4, l15 = lane & 15;

    const u16* im = in + (size_t)m * NPX * 64;
    const int pxA = base + w * 16 + l15;
    const int yA = pxA / W, xA = pxA - yA * W;
    const bool pxok = (pxA < NPX);

    f32x4 acc[4];
#pragma unroll
    for (int nt = 0; nt < 4; ++nt) acc[nt] = f32x4{0.f, 0.f, 0.f, 0.f};

#pragma unroll
    for (int tap = 0; tap < 9; ++tap) {
        const int dy = tap / 3 - 1, dx = tap % 3 - 1;
        const bool valid = pxok && (yA + dy >= 0) && (yA + dy < H)
                                && (xA + dx >= 0) && (xA + dx < W);
        const u16* ap = im + (size_t)(pxA + dy * W + dx) * 64;
        FragU a0, a1;
        if (valid) {
            a0 = *(const FragU*)(ap + q * 8);
            a1 = *(const FragU*)(ap + 32 + q * 8);
        } else {
#pragma unroll
            for (int jj = 0; jj < 8; ++jj) { a0.u[jj] = 0; a1.u[jj] = 0; }
        }
#pragma unroll
        for (int nt = 0; nt < 4; ++nt) {
            const u16* bp = wbf + tap * 4096 + (nt * 16 + l15) * 64;
            FragU b0 = *(const FragU*)(bp + q * 8);
            FragU b1 = *(const FragU*)(bp + 32 + q * 8);
            acc[nt] = __builtin_amdgcn_mfma_f32_16x16x32_bf16(a0.v, b0.v, acc[nt], 0, 0, 0);
            acc[nt] = __builtin_amdgcn_mfma_f32_16x16x32_bf16(a1.v, b1.v, acc[nt], 0, 0, 0);
        }
    }

#pragma unroll
    for (int nt = 0; nt < 4; ++nt) {
        const float bb = bias[nt * 16 + l15];
#pragma unroll
        for (int e = 0; e < 4; ++e) {
            int pxs = base + w * 16 + q * 4 + e;
            if (pxs < NPX)
                out[((size_t)m * NPX + pxs) * 64 + nt * 16 + l15] =
                    f2bf(fmaxf(acc[nt][e] + bb, 0.f));
        }
    }
}

// ================= MLP (r8-proven 512-block structure; global weight frags) =
__global__ __launch_bounds__(256, 2) void mlp_mfma_kernel(
    const float* __restrict__ lf, const float* __restrict__ flow,
    const u16* __restrict__ feat,   // [bs][2016][64] bf16
    const u16* __restrict__ w1t, const u16* __restrict__ w2t,
    const float* __restrict__ w1, const float* __restrict__ b1,
    const float* __restrict__ b2,
    const float* __restrict__ w3, const float* __restrict__ b3g,
    const float* __restrict__ cw, const float* __restrict__ cbg,
    float* __restrict__ nv_out, float* __restrict__ cf_out)
{
    constexpr int SBS = 72;
    __shared__ __align__(16) float s_vec[7 * 64];
    __shared__ __align__(16) float s_flow[256];
    __shared__ __align__(16) float s_epi[256];
    __shared__ __align__(16) u16 s_base[256 * SBS];

    const int t = threadIdx.x;
    const int blk = blockIdx.x;
    const int bs = blk >> 7;
    const int n0 = (blk & 127) * 8;
    const int b = bs >> 1, s = bs & 1;
    const int w = t >> 6, lane = t & 63, q = lane >> 4, l15 = lane & 15;

    if (t < 64) {
        s_vec[t]       = b1[t];
        s_vec[64 + t]  = b2[t];
        s_vec[128 + t] = w3[t];
        s_vec[192 + t] = cw[t];
        s_vec[256 + t] = w1[t];            // row 0: flow weight
        s_vec[320 + t] = w1[65 * 64 + t];  // row 65: spatial
        s_vec[384 + t] = w1[66 * 64 + t];  // row 66: ang
    }
    {
        int nl = t >> 5, k = t & 31;
        int n = n0 + nl;
        int a = (bs * 32 + (n >> 5)) * 63 + (n & 31) + k;
        s_flow[t] = flow[a];
        s_epi[t]  = lf[a];
    }
    __syncthreads();

    const float b3s = b3g[0];
    const float cbs = cbg[0];

    // layer-1 weight frags: aligned 16B loads from pre-transposed global bf16
    FragU w1b[2][4];
#pragma unroll
    for (int ks = 0; ks < 2; ++ks)
#pragma unroll
        for (int nt = 0; nt < 4; ++nt)
            w1b[ks][nt] = *(const FragU*)(w1t + (nt * 16 + l15) * 64 + ks * 32 + q * 8);

    float w1r0pl[4], w1r65pl[4], b1pl[4];
#pragma unroll
    for (int nt = 0; nt < 4; ++nt) {
        int j1 = nt * 16 + l15;
        w1r0pl[nt]  = s_vec[256 + j1];
        w1r65pl[nt] = s_vec[320 + j1];
        b1pl[nt]    = s_vec[j1];
    }

#pragma unroll
    for (int mt = 0; mt < 4; ++mt) {
        const int rbase = w * 64 + mt * 16;
        FragU af[2];
        {
            int r = rbase + l15;
            int n = n0 + (r >> 5);
            int pos = (n >> 5) * 63 + (n & 31) + (r & 31);
            const u16* fp = feat + ((size_t)bs * 2016 + pos) * 64;
            af[0] = *(const FragU*)(fp + q * 8);
            af[1] = *(const FragU*)(fp + 32 + q * 8);
        }
        f32x4 flow4 = *(const f32x4*)(s_flow + rbase + q * 4);
#pragma unroll
        for (int nt = 0; nt < 4; ++nt) {
            f32x4 d = {0.f, 0.f, 0.f, 0.f};
            d = __builtin_amdgcn_mfma_f32_16x16x32_bf16(af[0].v, w1b[0][nt].v, d, 0, 0, 0);
            d = __builtin_amdgcn_mfma_f32_16x16x32_bf16(af[1].v, w1b[1][nt].v, d, 0, 0, 0);
#pragma unroll
            for (int e = 0; e < 4; ++e) {
                int r = rbase + q * 4 + e;
                int k = r & 31;
                float val = d[e] + flow4[e] * w1r0pl[nt]
                          + (float)(k - 16) * w1r65pl[nt] + b1pl[nt];
                s_base[r * SBS + nt * 16 + l15] = f2bf(val);
            }
        }
    }
    __syncthreads();

    // layer-2 weight frags (A = W2^T) from global
    FragU w2a[4][2];
#pragma unroll
    for (int mt = 0; mt < 4; ++mt)
#pragma unroll
        for (int ks = 0; ks < 2; ++ks)
            w2a[mt][ks] = *(const FragU*)(w2t + (mt * 16 + l15) * 64 + ks * 32 + q * 8);

    float w66pl[2][8];
#pragma unroll
    for (int ks = 0; ks < 2; ++ks)
#pragma unroll
        for (int jj = 0; jj < 8; ++jj)
            w66pl[ks][jj] = s_vec[384 + ks * 32 + q * 8 + jj];

    float b2pl[4][4], w3pl[4][4], cwpl[4][4];
#pragma unroll
    for (int mt = 0; mt < 4; ++mt)
#pragma unroll
        for (int e = 0; e < 4; ++e) {
            b2pl[mt][e] = s_vec[64 + mt * 16 + q * 4 + e];
            w3pl[mt][e] = s_vec[128 + mt * 16 + q * 4 + e];
            cwpl[mt][e] = s_vec[192 + mt * 16 + q * 4 + e];
        }
    float epi_pl[4];
#pragma unroll
    for (int nt = 0; nt < 4; ++nt) epi_pl[nt] = s_epi[w * 64 + nt * 16 + l15];

    for (int v = 0; v < 7; ++v) {
        float ang = (s == 0) ? -(float)(v + 1) : (float)(7 - v);
        f32x4 acc[4][4];
#pragma unroll
        for (int nt = 0; nt < 4; ++nt) {
            FragU bfr[2];
#pragma unroll
            for (int ks = 0; ks < 2; ++ks) {
                const u16x8 raw = *(const u16x8*)(s_base + (w * 64 + nt * 16 + l15) * SBS + ks * 32 + q * 8);
#pragma unroll
                for (int jj = 0; jj < 8; ++jj) {
                    float xv = bf2f(raw[jj]);
                    float hv = fmaxf(xv + ang * w66pl[ks][jj], 0.f);
                    bfr[ks].u[jj] = f2bf(hv);
                }
            }
#pragma unroll
            for (int mt = 0; mt < 4; ++mt) {
                f32x4 d = {0.f, 0.f, 0.f, 0.f};
                d = __builtin_amdgcn_mfma_f32_16x16x32_bf16(w2a[mt][0].v, bfr[0].v, d, 0, 0, 0);
                d = __builtin_amdgcn_mfma_f32_16x16x32_bf16(w2a[mt][1].v, bfr[1].v, d, 0, 0, 0);
                acc[mt][nt] = d;
            }
        }
        float wl[4], cfl[4];
#pragma unroll
        for (int nt = 0; nt < 4; ++nt) {
            float wls = 0.f, cfs = 0.f;
#pragma unroll
            for (int mt = 0; mt < 4; ++mt)
#pragma unroll
                for (int e = 0; e < 4; ++e) {
                    float h2 = fmaxf(acc[mt][nt][e] + b2pl[mt][e], 0.f);
                    wls += h2 * w3pl[mt][e];
                    cfs += h2 * cwpl[mt][e];
                }
            wls += __shfl_xor(wls, 16); wls += __shfl_xor(wls, 32);
            cfs += __shfl_xor(cfs, 16); cfs += __shfl_xor(cfs, 32);
            wl[nt]  = wls + b3s;
            cfl[nt] = cfs;
        }
#pragma unroll
        for (int ni = 0; ni < 2; ++ni) {
            float a0 = wl[ni * 2], a1 = wl[ni * 2 + 1];
            float mx = fmaxf(a0, a1);
#pragma unroll
            for (int msk = 1; msk <= 8; msk <<= 1) mx = fmaxf(mx, __shfl_xor(mx, msk));
            float e0 = __expf(a0 - mx), e1 = __expf(a1 - mx);
            float ssum = e0 + e1;
            float nvp = e0 * epi_pl[ni * 2] + e1 * epi_pl[ni * 2 + 1];
            float cfp = cfl[ni * 2] + cfl[ni * 2 + 1];
#pragma unroll
            for (int msk = 1; msk <= 8; msk <<= 1) {
                ssum += __shfl_xor(ssum, msk);
                nvp  += __shfl_xor(nvp, msk);
                cfp  += __shfl_xor(cfp, msk);
            }
            if (lane == 0) {
                int n = n0 + w * 2 + ni;
                size_t idx = ((size_t)(b * 7 + v) * 2 + s) * 1024 + n;
                nv_out[idx] = nvp / ssum;
                cf_out[idx] = cfp * (1.f / 32.f) + cbs;
            }
        }
    }
}

// ================= combine (r4-verified) ===================================
__global__ void combine_kernel(const float* __restrict__ nv, const float* __restrict__ cf,
                               float* __restrict__ novel) {
    int tid = blockIdx.x * 256 + threadIdx.x;
    if (tid >= 2 * 7 * 1024) return;
    int n = tid & 1023;
    int bv = tid >> 10;
    size_t i0 = ((size_t)bv * 2 + 0) * 1024 + n;
    size_t i1 = ((size_t)bv * 2 + 1) * 1024 + n;
    float c0 = cf[i0], c1 = cf[i1];
    float mx = fmaxf(c0, c1);
    float e0 = __expf(c0 - mx), e1 = __expf(c1 - mx);
    novel[tid] = (e0 * nv[i0] + e1 * nv[i1]) / (e0 + e1);
}

// ================= convlast: 64 -> 1 + bias + residual =====================
__global__ __launch_bounds__(256) void convlast_kernel(
    const u16* __restrict__ in,     // [14][1024][64] bf16 ch-last
    const float* __restrict__ wts,  // [64][9]
    const float* __restrict__ bias, // [1]
    const float* __restrict__ resid,// [14][1024] f32
    float* __restrict__ out)        // [14][1024] f32
{
    __shared__ float sw3[576];
    const int t = threadIdx.x;
    for (int i = t; i < 576; i += 256) sw3[i] = wts[i];
    __syncthreads();

    const int tid = blockIdx.x * 256 + t;
    const int m = tid >> 10, p = tid & 1023;
    const int y = p >> 5, x = p & 31;
    float a = bias[0] + resid[tid];
    const u16* im = in + ((size_t)m * 1024 + p) * 64;
#pragma unroll
    for (int dy = 0; dy < 3; ++dy) {
        int yy = y + dy - 1;
        if (yy < 0 || yy >= 32) continue;
#pragma unroll
        for (int dx = 0; dx < 3; ++dx) {
            int xx = x + dx - 1;
            if (xx < 0 || xx >= 32) continue;
            const u16* ip = im + (size_t)((dy - 1) * 32 + (dx - 1)) * 64;
            const int tap = dy * 3 + dx;
#pragma unroll
            for (int cg = 0; cg < 8; ++cg) {
                u16x8 raw = *(const u16x8*)(ip + cg * 8);
#pragma unroll
                for (int e = 0; e < 8; ++e)
                    a = fmaf(bf2f(raw[e]), sw3[(cg * 8 + e) * 9 + tap], a);
            }
        }
    }
    out[tid] = a;
}

// ---------------- launch ----------------
extern "C" void kernel_launch(void* const* d_in, const int* in_sizes, int n_in,
                              void* d_out, int out_size, void* d_ws, size_t ws_size,
                              hipStream_t stream) {
    const float* lf   = (const float*)d_in[0];
    const float* flow = (const float*)d_in[1];
    const float* wp   = (const float*)d_in[2];
    const float* pl   = (const float*)d_in[3];
    const float* pr   = (const float*)d_in[4];
    float* ws = (float*)d_ws;

    prep_kernel<<<128, 256, 0, stream>>>(
        (const float*)d_in[7], (const float*)d_in[9], (const float*)d_in[21],
        (const float*)d_in[11], (const float*)d_in[13],
        (u16*)(ws + WB2F), (u16*)(ws + WB3F), (u16*)(ws + WBV2),
        (u16*)(ws + W1T), (u16*)(ws + W2T));

    // feature net (4 images, 32x63, ch-last bf16 pipeline)
    conv1_kernel<63, 2016><<<dim3(8, 8, 4), 256, 0, stream>>>(
        flow, lf, wp, (const float*)d_in[5], (const float*)d_in[6],
        (u16*)(ws + X1));
    convmfma_kernel<63, 2016><<<dim3(32, 4), 256, 0, stream>>>(
        (const u16*)(ws + X1), (const u16*)(ws + WB2F), (const float*)d_in[8],
        (u16*)(ws + X2));
    convmfma_kernel<63, 2016><<<dim3(32, 4), 256, 0, stream>>>(
        (const u16*)(ws + X2), (const u16*)(ws + WB3F), (const float*)d_in[10],
        (u16*)(ws + FEATBF));

    // MLP + softmax + epi -> nv/cf
    mlp_mfma_kernel<<<512, 256, 0, stream>>>(
        lf, flow, (const u16*)(ws + FEATBF),
        (const u16*)(ws + W1T), (const u16*)(ws + W2T),
        (const float*)d_in[11], (const float*)d_in[12],
        (const float*)d_in[14],
        (const float*)d_in[15], (const float*)d_in[16],
        (const float*)d_in[17], (const float*)d_in[18],
        ws + NVOFF, ws + CFOFF);

    combine_kernel<<<56, 256, 0, stream>>>(ws + NVOFF, ws + CFOFF, ws + NOVEL);

    // refinement net (14 images, 32x32)
    conv1_kernel<32, 1024><<<dim3(8, 4, 14), 256, 0, stream>>>(
        ws + NOVEL, pl, pr, (const float*)d_in[19], (const float*)d_in[20],
        (u16*)(ws + Y1));
    convmfma_kernel<32, 1024><<<dim3(16, 14), 256, 0, stream>>>(
        (const u16*)(ws + Y1), (const u16*)(ws + WBV2), (const float*)d_in[22],
        (u16*)(ws + Y2));
    convlast_kernel<<<56, 256, 0, stream>>>(
        (const u16*)(ws + Y2), (const float*)d_in[23], (const float*)d_in[24],
        ws + NOVEL, (float*)d_out);
}